// Round 6
// baseline (240.991 us; speedup 1.0000x reference)
//
#include <hip/hip_runtime.h>
#include <hip/hip_bf16.h>

// LearnableVQ forward on MI355X — v3: 1-wave blocks, no LDS staging, no hot barriers.
// B=8 H=8 L=4096 DK=64 S=512. Inputs f32; output f32, concatenated:
//   vecs_hat[B,H,L,DK] | z[B,H,L] | l_commit | l_codebook | errs2[B,H,L]
// vecs_hat = c[h,z]; l_codebook = 0. Distance GEMM = bf16 3-term split MFMA
// (hi*hi + hi*lo + lo*hi), per-lane top-2 fold, exact f64 top-2 refine.

#define Bc 8
#define Hc 8
#define Lc 4096
#define DKc 64
#define Sc 512

typedef __attribute__((ext_vector_type(8))) short bf16x8;
typedef __attribute__((ext_vector_type(4))) float f32x4;

// ---------------- ws layout (bytes) ----------------
#define WS_C_OFF    0u          // H*S*DK f32           = 1,048,576
#define WS_C2_OFF   1048576u    // H*S f32              =    16,384
#define WS_CBH_OFF  1064960u    // H*S*DK bf16 hi (swz) =   524,288
#define WS_CBL_OFF  1589248u    // H*S*DK bf16 lo (swz) =   524,288
#define WS_PART_OFF 2113536u    // 8192 f32             =    32,768
#define NPART       8192

__device__ __forceinline__ unsigned short f32_to_bf16_rne(float x) {
    unsigned u = __float_as_uint(x);
    unsigned r = (u + 0x7FFFu + ((u >> 16) & 1u)) >> 16;
    return (unsigned short)r;
}
__device__ __forceinline__ float bf16_hi_f32(unsigned short h) {
    return __uint_as_float(((unsigned)h) << 16);
}

// ---------------- prep: normalize codebook; c2; pre-split pre-swizzled bf16 ----------------
__global__ __launch_bounds__(256) void prep_kernel(
        const float* __restrict__ c_sum,
        const float* __restrict__ c_count,
        float* __restrict__ c,
        float* __restrict__ c2,
        unsigned short* __restrict__ cbh,
        unsigned short* __restrict__ cbl) {
    int row  = (blockIdx.x * blockDim.x + threadIdx.x) >> 6;   // h*512 + s
    int lane = threadIdx.x & 63;
    float cnt = c_count[row];
    float inv = 1.0f / fmaxf(cnt, 0.01f);
    float val = c_sum[row * DKc + lane] * inv;
    c[row * DKc + lane] = val;
    unsigned short hi = f32_to_bf16_rne(val);
    unsigned short lo = f32_to_bf16_rne(val - bf16_hi_f32(hi));
    int s = row & (Sc - 1);
    size_t hbase = (size_t)(row >> 9) * (Sc * 128);            // bytes per head
    int boff = (s * 128 + lane * 2) ^ ((s & 7) << 4);          // swizzled layout
    *(unsigned short*)((char*)cbh + hbase + boff) = hi;
    *(unsigned short*)((char*)cbl + hbase + boff) = lo;
    float sq = val * val;
    #pragma unroll
    for (int off = 32; off; off >>= 1) sq += __shfl_xor(sq, off);
    if (lane == 0) c2[row] = sq;
}

// ---------------- main: 1 wave = 32 rows; B fragments straight from L2 ----------------
__global__ __launch_bounds__(64, 3) void vq_mfma_kernel(
        const float* __restrict__ vecs,
        const float* __restrict__ c,
        const float* __restrict__ c2,
        const unsigned short* __restrict__ cbh,
        const unsigned short* __restrict__ cbl,
        const float* __restrict__ loss_mask,
        float* __restrict__ out_vh,
        float* __restrict__ out_z,
        float* __restrict__ out_err,
        float* __restrict__ partials) {
    __shared__ int2 top2s[32];          // 256 B

    const int l   = threadIdx.x;        // 0..63
    const int col = l & 15;
    const int ksl = l >> 4;             // 0..3
    const int bh  = blockIdx.y;         // b*H + h
    const int h   = bh & (Hc - 1);
    const int b   = bh >> 3;
    const int lt  = blockIdx.x;         // 0..127 (32 rows each)

    const float* Avec  = vecs + ((size_t)bh * Lc + (size_t)lt * 32) * DKc;
    const float* Bp    = c + (size_t)h * Sc * DKc;
    const float* c2h   = c2 + h * Sc;
    const char*  cbh_h = (const char*)cbh + (size_t)h * (Sc * 128);
    const char*  cbl_h = (const char*)cbl + (size_t)h * (Sc * 128);

    // ---- A fragments: rows (rt*16 + col), dims ks*32 + ksl*8 .. +7 ----
    bf16x8 fah[2][2], fal[2][2];
    #pragma unroll
    for (int rt = 0; rt < 2; ++rt) {
        const float* Ar = Avec + (size_t)((rt << 4) + col) * DKc;
        #pragma unroll
        for (int ks = 0; ks < 2; ++ks) {
            int k0 = (ks << 5) + (ksl << 3);
            float4 p0 = *reinterpret_cast<const float4*>(Ar + k0);
            float4 p1 = *reinterpret_cast<const float4*>(Ar + k0 + 4);
            float e8[8] = {p0.x, p0.y, p0.z, p0.w, p1.x, p1.y, p1.z, p1.w};
            bf16x8 hv, lv;
            #pragma unroll
            for (int i = 0; i < 8; ++i) {
                unsigned short hi = f32_to_bf16_rne(e8[i]);
                hv[i] = (short)hi;
                lv[i] = (short)f32_to_bf16_rne(e8[i] - bf16_hi_f32(hi));
            }
            fah[rt][ks] = hv;
            fal[rt][ks] = lv;
        }
    }

    // per-lane top-2: rows (rt*16 + ksl*4 + r), col codes
    float v1[2][4], v2[2][4];
    int   i1[2][4], i2[2][4];
    #pragma unroll
    for (int rt = 0; rt < 2; ++rt)
        #pragma unroll
        for (int r = 0; r < 4; ++r) { v1[rt][r] = 3.0e38f; v2[rt][r] = 3.0e38f; i1[rt][r] = 0; i2[rt][r] = 0; }

    for (int chunk = 0; chunk < 4; ++chunk) {
        float ccv[8];
        #pragma unroll
        for (int j = 0; j < 8; ++j) ccv[j] = c2h[(chunk << 7) + (j << 4) + col];
        const char* ph = cbh_h + (chunk << 14);
        const char* pl = cbl_h + (chunk << 14);

        auto ZERO = [&](f32x4 (&a)[2]) {
            a[0] = (f32x4){0.f, 0.f, 0.f, 0.f};
            a[1] = (f32x4){0.f, 0.f, 0.f, 0.f};
        };
        auto STEP = [&](int j, f32x4 (&acc)[2]) {
            int crow = (j << 4) + col;
            int o0 = ((crow << 7) + (ksl << 4)) ^ ((crow & 7) << 4);
            bf16x8 h0 = *reinterpret_cast<const bf16x8*>(ph + o0);
            bf16x8 h1 = *reinterpret_cast<const bf16x8*>(ph + (o0 ^ 64));
            bf16x8 g0 = *reinterpret_cast<const bf16x8*>(pl + o0);
            bf16x8 g1 = *reinterpret_cast<const bf16x8*>(pl + (o0 ^ 64));
            #pragma unroll
            for (int rt = 0; rt < 2; ++rt) {
                acc[rt] = __builtin_amdgcn_mfma_f32_16x16x32_bf16(fah[rt][0], h0, acc[rt], 0, 0, 0);
                acc[rt] = __builtin_amdgcn_mfma_f32_16x16x32_bf16(fah[rt][1], h1, acc[rt], 0, 0, 0);
                acc[rt] = __builtin_amdgcn_mfma_f32_16x16x32_bf16(fal[rt][0], h0, acc[rt], 0, 0, 0);
                acc[rt] = __builtin_amdgcn_mfma_f32_16x16x32_bf16(fal[rt][1], h1, acc[rt], 0, 0, 0);
                acc[rt] = __builtin_amdgcn_mfma_f32_16x16x32_bf16(fah[rt][0], g0, acc[rt], 0, 0, 0);
                acc[rt] = __builtin_amdgcn_mfma_f32_16x16x32_bf16(fah[rt][1], g1, acc[rt], 0, 0, 0);
            }
        };
        auto FOLD = [&](int j, f32x4 (&acc)[2]) {
            int code = (chunk << 7) + (j << 4) + col;
            float cc = ccv[j];
            #pragma unroll
            for (int rt = 0; rt < 2; ++rt)
                #pragma unroll
                for (int r = 0; r < 4; ++r) {
                    float d = fmaf(-2.0f, acc[rt][r], cc);
                    if (d < v1[rt][r]) { v2[rt][r] = v1[rt][r]; i2[rt][r] = i1[rt][r]; v1[rt][r] = d; i1[rt][r] = code; }
                    else if (d < v2[rt][r]) { v2[rt][r] = d; i2[rt][r] = code; }
                }
        };

        // 2-slot rotation: fold j while j+1..j+2's MFMAs are in flight
        f32x4 accA[2], accB[2];
        ZERO(accA); STEP(0, accA);
        ZERO(accB); STEP(1, accB);
        FOLD(0, accA); ZERO(accA); STEP(2, accA);
        FOLD(1, accB); ZERO(accB); STEP(3, accB);
        FOLD(2, accA); ZERO(accA); STEP(4, accA);
        FOLD(3, accB); ZERO(accB); STEP(5, accB);
        FOLD(4, accA); ZERO(accA); STEP(6, accA);
        FOLD(5, accB); ZERO(accB); STEP(7, accB);
        FOLD(6, accA);
        FOLD(7, accB);
    }

    // ---- cross-lane top-2 merge over the 16 cols sharing each row ----
    #pragma unroll
    for (int off = 1; off <= 8; off <<= 1) {
        #pragma unroll
        for (int rt = 0; rt < 2; ++rt)
            #pragma unroll
            for (int r = 0; r < 4; ++r) {
                float w1 = __shfl_xor(v1[rt][r], off);
                int   j1 = __shfl_xor(i1[rt][r], off);
                float w2 = __shfl_xor(v2[rt][r], off);
                int   j2 = __shfl_xor(i2[rt][r], off);
                bool firstWins = (w1 < v1[rt][r]) || (w1 == v1[rt][r] && j1 < i1[rt][r]);
                if (firstWins) {
                    float nv2; int ni2;
                    if (v1[rt][r] < w2 || (v1[rt][r] == w2 && i1[rt][r] < j2)) { nv2 = v1[rt][r]; ni2 = i1[rt][r]; }
                    else                                                       { nv2 = w2;        ni2 = j2; }
                    v1[rt][r] = w1; i1[rt][r] = j1; v2[rt][r] = nv2; i2[rt][r] = ni2;
                } else {
                    if (w1 < v2[rt][r] || (w1 == v2[rt][r] && j1 < i2[rt][r])) { v2[rt][r] = w1; i2[rt][r] = j1; }
                }
            }
    }
    if (col == 0) {
        #pragma unroll
        for (int rt = 0; rt < 2; ++rt)
            #pragma unroll
            for (int r = 0; r < 4; ++r)
                top2s[(rt << 4) + (ksl << 2) + r] = make_int2(i1[rt][r], i2[rt][r]);
    }
    __syncthreads();    // single wave: cheap

    // ---- refine: 4 lanes per row (each owns its k-slice); f64 delta; f32 err ----
    double macc = 0.0;
    #pragma unroll
    for (int rt = 0; rt < 2; ++rt) {
        int  row  = (rt << 4) + col;
        int  lrow = lt * 32 + row;
        long grow = (long)bh * Lc + lrow;
        int2 zz   = top2s[row];
        const float* Ar = Avec + (size_t)row * DKc;
        const float* C1 = Bp + (size_t)zz.x * DKc;
        const float* C2 = Bp + (size_t)zz.y * DKc;
        int k0 = ksl << 3;
        f32x4 va[4], ca[4], cb[4];
        #pragma unroll
        for (int ks = 0; ks < 2; ++ks) {
            va[ks * 2 + 0] = *reinterpret_cast<const f32x4*>(Ar + (ks << 5) + k0);
            va[ks * 2 + 1] = *reinterpret_cast<const f32x4*>(Ar + (ks << 5) + k0 + 4);
            ca[ks * 2 + 0] = *reinterpret_cast<const f32x4*>(C1 + (ks << 5) + k0);
            ca[ks * 2 + 1] = *reinterpret_cast<const f32x4*>(C1 + (ks << 5) + k0 + 4);
            cb[ks * 2 + 0] = *reinterpret_cast<const f32x4*>(C2 + (ks << 5) + k0);
            cb[ks * 2 + 1] = *reinterpret_cast<const f32x4*>(C2 + (ks << 5) + k0 + 4);
        }
        // d1 - d2 = sum (c1-c2)*((c1+c2) - 2v) in f64
        double dd = 0.0;
        #pragma unroll
        for (int q = 0; q < 4; ++q)
            #pragma unroll
            for (int m = 0; m < 4; ++m) {
                double a = (double)ca[q][m], bb = (double)cb[q][m], vv = (double)va[q][m];
                dd = fma(a - bb, (a + bb) - 2.0 * vv, dd);
            }
        dd += __shfl_xor(dd, 16);
        dd += __shfl_xor(dd, 32);
        bool second = (dd > 0.0) || (dd == 0.0 && zz.y < zz.x);
        int zsel = second ? zz.y : zz.x;
        f32x4 cs[4];
        #pragma unroll
        for (int q = 0; q < 4; ++q) cs[q] = second ? cb[q] : ca[q];
        float e = 0.f;
        #pragma unroll
        for (int q = 0; q < 4; ++q)
            #pragma unroll
            for (int m = 0; m < 4; ++m) {
                float tdiff = va[q][m] - cs[q][m];
                e = fmaf(tdiff, tdiff, e);
            }
        e += __shfl_xor(e, 16);
        e += __shfl_xor(e, 32);
        float* Or = out_vh + (size_t)grow * DKc;
        *reinterpret_cast<f32x4*>(Or + k0)          = cs[0];
        *reinterpret_cast<f32x4*>(Or + k0 + 4)      = cs[1];
        *reinterpret_cast<f32x4*>(Or + 32 + k0)     = cs[2];
        *reinterpret_cast<f32x4*>(Or + 32 + k0 + 4) = cs[3];
        if (ksl == 0) {
            out_z[grow]   = (float)zsel;
            out_err[grow] = e;
            macc += (double)loss_mask[b * Lc + lrow] * (double)e;
        }
    }
    // block partial over the 16 row-owner lanes (others contribute 0)
    #pragma unroll
    for (int off = 1; off <= 8; off <<= 1) macc += __shfl_xor(macc, off);
    if (l == 0) partials[blockIdx.y * gridDim.x + blockIdx.x] = (float)macc;
}

// ---------------- finalize ----------------
__global__ __launch_bounds__(256) void finalize_kernel(
        const float* __restrict__ partials, int n,
        float* __restrict__ out_lcommit, float* __restrict__ out_lcode) {
    __shared__ double sh[256];
    double a = 0.0;
    for (int i = threadIdx.x; i < n; i += 256) a += (double)partials[i];
    sh[threadIdx.x] = a;
    __syncthreads();
    for (int s = 128; s; s >>= 1) {
        if (threadIdx.x < s) sh[threadIdx.x] += sh[threadIdx.x + s];
        __syncthreads();
    }
    if (threadIdx.x == 0) {
        double lc = sh[0] / (double)(Bc * Lc);
        *out_lcommit = (float)lc;
        *out_lcode   = 0.0f;
    }
}

extern "C" void kernel_launch(void* const* d_in, const int* in_sizes, int n_in,
                              void* d_out, int out_size, void* d_ws, size_t ws_size,
                              hipStream_t stream) {
    const float* vecs      = (const float*)d_in[0];
    const float* c_sum     = (const float*)d_in[1];
    const float* c_count   = (const float*)d_in[2];
    const float* loss_mask = (const float*)d_in[3];
    (void)in_sizes; (void)n_in; (void)out_size; (void)ws_size;

    char* ws = (char*)d_ws;
    float*          c        = (float*)(ws + WS_C_OFF);
    float*          c2       = (float*)(ws + WS_C2_OFF);
    unsigned short* cbh      = (unsigned short*)(ws + WS_CBH_OFF);
    unsigned short* cbl      = (unsigned short*)(ws + WS_CBL_OFF);
    float*          partials = (float*)(ws + WS_PART_OFF);

    float* out = (float*)d_out;
    float* out_vh      = out;                                   // B*H*L*DK
    float* out_z       = out + (size_t)Bc * Hc * Lc * DKc;      // B*H*L
    float* out_lcommit = out_z + (size_t)Bc * Hc * Lc;          // 1
    float* out_lcode   = out_lcommit + 1;                       // 1
    float* out_err     = out_lcode + 1;                         // B*H*L

    prep_kernel<<<(Hc * Sc * 64) / 256, 256, 0, stream>>>(c_sum, c_count, c, c2, cbh, cbl);

    dim3 g2(Lc / 32, Bc * Hc);          // (128, 64) -> 8192 one-wave blocks
    vq_mfma_kernel<<<g2, 64, 0, stream>>>(vecs, c, c2, cbh, cbl, loss_mask,
                                          out_vh, out_z, out_err, partials);

    finalize_kernel<<<1, 256, 0, stream>>>(partials, NPART, out_lcommit, out_lcode);
}

// Round 7
// 180.980 us; speedup vs baseline: 1.3316x; 1.3316x over previous
//
#include <hip/hip_runtime.h>
#include <hip/hip_bf16.h>

// LearnableVQ forward on MI355X — v4: r5 LDS structure + async reg-staged
// prefetch (T14) + XCD head-affinity block swizzle + acc-init=-c2/2 fold +
// fast all-lane refine.
// B=8 H=8 L=4096 DK=64 S=512. Inputs f32; output f32, concatenated:
//   vecs_hat[B,H,L,DK] | z[B,H,L] | l_commit | l_codebook | errs2[B,H,L]

#define Bc 8
#define Hc 8
#define Lc 4096
#define DKc 64
#define Sc 512

typedef __attribute__((ext_vector_type(8))) short bf16x8;
typedef __attribute__((ext_vector_type(8))) unsigned short u16x8;
typedef __attribute__((ext_vector_type(4))) float f32x4;

// ---------------- ws layout (bytes) ----------------
#define WS_C_OFF    0u          // H*S*DK f32           = 1,048,576
#define WS_C2_OFF   1048576u    // H*S f32              =    16,384
#define WS_CBH_OFF  1064960u    // H*S*DK bf16 hi (swz) =   524,288
#define WS_CBL_OFF  1589248u    // H*S*DK bf16 lo (swz) =   524,288
#define WS_PART_OFF 2113536u    // 8192 f32             =    32,768
#define NPART       8192

__device__ __forceinline__ unsigned short f32_to_bf16_rne(float x) {
    unsigned u = __float_as_uint(x);
    unsigned r = (u + 0x7FFFu + ((u >> 16) & 1u)) >> 16;
    return (unsigned short)r;
}
__device__ __forceinline__ float bf16_hi_f32(unsigned short h) {
    return __uint_as_float(((unsigned)h) << 16);
}

// ---------------- prep: normalize codebook; c2; pre-split pre-swizzled bf16 ----------------
__global__ __launch_bounds__(256) void prep_kernel(
        const float* __restrict__ c_sum,
        const float* __restrict__ c_count,
        float* __restrict__ c,
        float* __restrict__ c2,
        unsigned short* __restrict__ cbh,
        unsigned short* __restrict__ cbl) {
    int row  = (blockIdx.x * blockDim.x + threadIdx.x) >> 6;   // h*512 + s
    int lane = threadIdx.x & 63;
    float cnt = c_count[row];
    float inv = 1.0f / fmaxf(cnt, 0.01f);
    float val = c_sum[row * DKc + lane] * inv;
    c[row * DKc + lane] = val;
    unsigned short hi = f32_to_bf16_rne(val);
    unsigned short lo = f32_to_bf16_rne(val - bf16_hi_f32(hi));
    int s = row & (Sc - 1);
    size_t hbase = (size_t)(row >> 9) * (Sc * 128);            // bytes per head
    int boff = (s * 128 + lane * 2) ^ ((s & 7) << 4);          // swizzled layout
    *(unsigned short*)((char*)cbh + hbase + boff) = hi;
    *(unsigned short*)((char*)cbl + hbase + boff) = lo;
    float sq = val * val;
    #pragma unroll
    for (int off = 32; off; off >>= 1) sq += __shfl_xor(sq, off);
    if (lane == 0) c2[row] = sq;
}

// ---------------- fused kernel: 4 waves, 128 rows, reg-prefetched B chunks ----------------
__global__ __launch_bounds__(256, 3) void vq_mfma_kernel(
        const float* __restrict__ vecs,
        const float* __restrict__ c,
        const float* __restrict__ c2,
        const unsigned short* __restrict__ cbh,
        const unsigned short* __restrict__ cbl,
        const float* __restrict__ loss_mask,
        float* __restrict__ out_vh,
        float* __restrict__ out_z,
        float* __restrict__ out_err,
        float* __restrict__ partials) {
    __shared__ unsigned short bhi[128 * DKc];   // 16 KiB (swizzled content)
    __shared__ unsigned short blo[128 * DKc];   // 16 KiB
    __shared__ float c2_lds[Sc];                //  2 KiB
    __shared__ int2  top2s[128];                //  1 KiB -> ~35.3 KiB total

    const int t   = threadIdx.x;
    const int l   = t & 63;
    const int w   = t >> 6;
    const int col = l & 15;
    const int ksl = l >> 4;

    // XCD head-affinity: consecutive-8 blocks round-robin XCDs; give XCD i head i.
    const int flat = blockIdx.x;        // 0..2047
    const int h    = flat & 7;
    const int idx  = flat >> 3;         // 0..255
    const int b    = idx >> 5;
    const int lt   = idx & 31;          // 128-row tile
    const int bh   = b * Hc + h;

    const float* Avec  = vecs + ((size_t)bh * Lc + (size_t)lt * 128) * DKc;
    const float* Bp    = c + (size_t)h * Sc * DKc;
    const char*  cbh_h = (const char*)cbh + (size_t)h * (Sc * 128);
    const char*  cbl_h = (const char*)cbl + (size_t)h * (Sc * 128);

    // ---- chunk-0 staging loads (issued first; return under A-convert) ----
    u16x8 sph[4], spl[4];
    {
        const char* sh0 = cbh_h + w * 4096;
        const char* sl0 = cbl_h + w * 4096;
        #pragma unroll
        for (int i = 0; i < 4; ++i) {
            sph[i] = *(const u16x8*)(sh0 + i * 1024 + l * 16);
            spl[i] = *(const u16x8*)(sl0 + i * 1024 + l * 16);
        }
    }

    // ---- A fragments: rows w*32 + rt*16 + col; convert to bf16 hi/lo in-reg ----
    bf16x8 fah[2][2], fal[2][2];
    #pragma unroll
    for (int rt = 0; rt < 2; ++rt) {
        const float* Ar = Avec + (size_t)((w << 5) + (rt << 4) + col) * DKc;
        #pragma unroll
        for (int ks = 0; ks < 2; ++ks) {
            int k0 = (ks << 5) + (ksl << 3);
            float4 p0 = *reinterpret_cast<const float4*>(Ar + k0);
            float4 p1 = *reinterpret_cast<const float4*>(Ar + k0 + 4);
            float e8[8] = {p0.x, p0.y, p0.z, p0.w, p1.x, p1.y, p1.z, p1.w};
            bf16x8 hv, lv;
            #pragma unroll
            for (int i = 0; i < 8; ++i) {
                unsigned short hi = f32_to_bf16_rne(e8[i]);
                hv[i] = (short)hi;
                lv[i] = (short)f32_to_bf16_rne(e8[i] - bf16_hi_f32(hi));
            }
            fah[rt][ks] = hv;
            fal[rt][ks] = lv;
        }
    }

    c2_lds[t]       = c2[h * Sc + t];
    c2_lds[t + 256] = c2[h * Sc + t + 256];

    // ---- write chunk 0 into LDS ----
    {
        char* dh = (char*)bhi + w * 4096;
        char* dl = (char*)blo + w * 4096;
        #pragma unroll
        for (int i = 0; i < 4; ++i) {
            *(u16x8*)(dh + i * 1024 + l * 16) = sph[i];
            *(u16x8*)(dl + i * 1024 + l * 16) = spl[i];
        }
    }
    __syncthreads();

    // per-lane top-2 MAX state over m = dot - c2/2  (argmin d == argmax m)
    float v1[2][4], v2[2][4];
    int   i1[2][4], i2[2][4];
    #pragma unroll
    for (int rt = 0; rt < 2; ++rt)
        #pragma unroll
        for (int r = 0; r < 4; ++r) { v1[rt][r] = -3.0e38f; v2[rt][r] = -3.0e38f; i1[rt][r] = 0; i2[rt][r] = 0; }

    for (int chunk = 0; chunk < 4; ++chunk) {
        // T14: issue next chunk's loads now; consumed after the read-barrier
        u16x8 nh[4], nl[4];
        if (chunk < 3) {
            const char* sh_ = cbh_h + ((chunk + 1) << 14) + w * 4096;
            const char* sl_ = cbl_h + ((chunk + 1) << 14) + w * 4096;
            #pragma unroll
            for (int i = 0; i < 4; ++i) {
                nh[i] = *(const u16x8*)(sh_ + i * 1024 + l * 16);
                nl[i] = *(const u16x8*)(sl_ + i * 1024 + l * 16);
            }
        }

        auto INIT = [&](int j, f32x4 (&a)[2]) {
            float m0 = -0.5f * c2_lds[(chunk << 7) + (j << 4) + col];
            a[0] = (f32x4){m0, m0, m0, m0};
            a[1] = (f32x4){m0, m0, m0, m0};
        };
        auto STEP = [&](int j, f32x4 (&acc)[2]) {
            int crow = (j << 4) + col;
            int o0 = ((crow << 7) + (ksl << 4)) ^ ((crow & 7) << 4);
            bf16x8 h0 = *reinterpret_cast<const bf16x8*>((const char*)bhi + o0);
            bf16x8 h1 = *reinterpret_cast<const bf16x8*>((const char*)bhi + (o0 ^ 64));
            bf16x8 g0 = *reinterpret_cast<const bf16x8*>((const char*)blo + o0);
            bf16x8 g1 = *reinterpret_cast<const bf16x8*>((const char*)blo + (o0 ^ 64));
            #pragma unroll
            for (int rt = 0; rt < 2; ++rt) {
                acc[rt] = __builtin_amdgcn_mfma_f32_16x16x32_bf16(fah[rt][0], h0, acc[rt], 0, 0, 0);
                acc[rt] = __builtin_amdgcn_mfma_f32_16x16x32_bf16(fah[rt][1], h1, acc[rt], 0, 0, 0);
                acc[rt] = __builtin_amdgcn_mfma_f32_16x16x32_bf16(fal[rt][0], h0, acc[rt], 0, 0, 0);
                acc[rt] = __builtin_amdgcn_mfma_f32_16x16x32_bf16(fal[rt][1], h1, acc[rt], 0, 0, 0);
                acc[rt] = __builtin_amdgcn_mfma_f32_16x16x32_bf16(fah[rt][0], g0, acc[rt], 0, 0, 0);
                acc[rt] = __builtin_amdgcn_mfma_f32_16x16x32_bf16(fah[rt][1], g1, acc[rt], 0, 0, 0);
            }
        };
        auto FOLD = [&](int j, f32x4 (&acc)[2]) {
            int code = (chunk << 7) + (j << 4) + col;
            #pragma unroll
            for (int rt = 0; rt < 2; ++rt)
                #pragma unroll
                for (int r = 0; r < 4; ++r) {
                    float m = acc[rt][r];
                    bool c1 = m > v1[rt][r];
                    bool c2b = m > v2[rt][r];
                    v2[rt][r] = fminf(fmaxf(m, v2[rt][r]), v1[rt][r]);   // med3
                    i2[rt][r] = c1 ? i1[rt][r] : (c2b ? code : i2[rt][r]);
                    v1[rt][r] = fmaxf(v1[rt][r], m);
                    i1[rt][r] = c1 ? code : i1[rt][r];
                }
        };

        // 2-slot rotation: fold j while j+1/j+2 MFMAs are in flight
        f32x4 accA[2], accB[2];
        INIT(0, accA); STEP(0, accA);
        INIT(1, accB); STEP(1, accB);
        FOLD(0, accA); INIT(2, accA); STEP(2, accA);
        FOLD(1, accB); INIT(3, accB); STEP(3, accB);
        FOLD(2, accA); INIT(4, accA); STEP(4, accA);
        FOLD(3, accB); INIT(5, accB); STEP(5, accB);
        FOLD(4, accA); INIT(6, accA); STEP(6, accA);
        FOLD(5, accB); INIT(7, accB); STEP(7, accB);
        FOLD(6, accA);
        FOLD(7, accB);

        __syncthreads();    // all waves done reading bhi/blo
        if (chunk < 3) {
            char* dh = (char*)bhi + w * 4096;
            char* dl = (char*)blo + w * 4096;
            #pragma unroll
            for (int i = 0; i < 4; ++i) {
                *(u16x8*)(dh + i * 1024 + l * 16) = nh[i];
                *(u16x8*)(dl + i * 1024 + l * 16) = nl[i];
            }
            __syncthreads();
        }
    }

    // ---- cross-lane top-2 merge (max) over the 16 cols sharing each row ----
    #pragma unroll
    for (int off = 1; off <= 8; off <<= 1) {
        #pragma unroll
        for (int rt = 0; rt < 2; ++rt)
            #pragma unroll
            for (int r = 0; r < 4; ++r) {
                float w1 = __shfl_xor(v1[rt][r], off);
                int   j1 = __shfl_xor(i1[rt][r], off);
                float w2 = __shfl_xor(v2[rt][r], off);
                int   j2 = __shfl_xor(i2[rt][r], off);
                bool firstWins = (w1 > v1[rt][r]) || (w1 == v1[rt][r] && j1 < i1[rt][r]);
                if (firstWins) {
                    float nv2; int ni2;
                    if (v1[rt][r] > w2 || (v1[rt][r] == w2 && i1[rt][r] < j2)) { nv2 = v1[rt][r]; ni2 = i1[rt][r]; }
                    else                                                        { nv2 = w2;        ni2 = j2; }
                    v1[rt][r] = w1; i1[rt][r] = j1; v2[rt][r] = nv2; i2[rt][r] = ni2;
                } else {
                    if (w1 > v2[rt][r] || (w1 == v2[rt][r] && j1 < i2[rt][r])) { v2[rt][r] = w1; i2[rt][r] = j1; }
                }
            }
    }
    if (col == 0) {
        #pragma unroll
        for (int rt = 0; rt < 2; ++rt)
            #pragma unroll
            for (int r = 0; r < 4; ++r)
                top2s[(w << 5) + (rt << 4) + (ksl << 2) + r] = make_int2(i1[rt][r], i2[rt][r]);
    }
    __syncthreads();

    // ---- refine: 4 lanes per row; exact f64 delta decides; f32 err; outputs ----
    double macc = 0.0;
    #pragma unroll
    for (int rt = 0; rt < 2; ++rt) {
        int  rloc = (w << 5) + (rt << 4) + col;     // block-local row 0..127
        int  lrow = lt * 128 + rloc;
        long grow = (long)bh * Lc + lrow;
        int2 zz   = top2s[rloc];
        const float* Ar = Avec + (size_t)rloc * DKc;
        const float* C1 = Bp + (size_t)zz.x * DKc;
        const float* C2 = Bp + (size_t)zz.y * DKc;
        int k0 = ksl << 3;
        f32x4 va[4], ca[4], cb[4];
        #pragma unroll
        for (int ks = 0; ks < 2; ++ks) {
            va[ks * 2 + 0] = *reinterpret_cast<const f32x4*>(Ar + (ks << 5) + k0);
            va[ks * 2 + 1] = *reinterpret_cast<const f32x4*>(Ar + (ks << 5) + k0 + 4);
            ca[ks * 2 + 0] = *reinterpret_cast<const f32x4*>(C1 + (ks << 5) + k0);
            ca[ks * 2 + 1] = *reinterpret_cast<const f32x4*>(C1 + (ks << 5) + k0 + 4);
            cb[ks * 2 + 0] = *reinterpret_cast<const f32x4*>(C2 + (ks << 5) + k0);
            cb[ks * 2 + 1] = *reinterpret_cast<const f32x4*>(C2 + (ks << 5) + k0 + 4);
        }
        double dd = 0.0;        // d1 - d2 = sum (c1-c2)*((c1+c2) - 2v)
        #pragma unroll
        for (int q = 0; q < 4; ++q)
            #pragma unroll
            for (int m = 0; m < 4; ++m) {
                double a = (double)ca[q][m], bb = (double)cb[q][m], vv = (double)va[q][m];
                dd = fma(a - bb, (a + bb) - 2.0 * vv, dd);
            }
        dd += __shfl_xor(dd, 16);
        dd += __shfl_xor(dd, 32);
        bool second = (dd > 0.0) || (dd == 0.0 && zz.y < zz.x);
        int zsel = second ? zz.y : zz.x;
        f32x4 cs[4];
        #pragma unroll
        for (int q = 0; q < 4; ++q) cs[q] = second ? cb[q] : ca[q];
        float e = 0.f;
        #pragma unroll
        for (int q = 0; q < 4; ++q)
            #pragma unroll
            for (int m = 0; m < 4; ++m) {
                float tdiff = va[q][m] - cs[q][m];
                e = fmaf(tdiff, tdiff, e);
            }
        e += __shfl_xor(e, 16);
        e += __shfl_xor(e, 32);
        float* Or = out_vh + (size_t)grow * DKc;
        *reinterpret_cast<f32x4*>(Or + k0)          = cs[0];
        *reinterpret_cast<f32x4*>(Or + k0 + 4)      = cs[1];
        *reinterpret_cast<f32x4*>(Or + 32 + k0)     = cs[2];
        *reinterpret_cast<f32x4*>(Or + 32 + k0 + 4) = cs[3];
        if (ksl == 0) {
            out_z[grow]   = (float)zsel;
            out_err[grow] = e;
            macc += (double)loss_mask[b * Lc + lrow] * (double)e;
        }
    }
    #pragma unroll
    for (int off = 1; off <= 8; off <<= 1) macc += __shfl_xor(macc, off);
    if (l == 0) partials[flat * 4 + w] = (float)macc;
}

// ---------------- finalize ----------------
__global__ __launch_bounds__(256) void finalize_kernel(
        const float* __restrict__ partials, int n,
        float* __restrict__ out_lcommit, float* __restrict__ out_lcode) {
    __shared__ double sh[256];
    double a = 0.0;
    for (int i = threadIdx.x; i < n; i += 256) a += (double)partials[i];
    sh[threadIdx.x] = a;
    __syncthreads();
    for (int s = 128; s; s >>= 1) {
        if (threadIdx.x < s) sh[threadIdx.x] += sh[threadIdx.x + s];
        __syncthreads();
    }
    if (threadIdx.x == 0) {
        double lc = sh[0] / (double)(Bc * Lc);
        *out_lcommit = (float)lc;
        *out_lcode   = 0.0f;
    }
}

extern "C" void kernel_launch(void* const* d_in, const int* in_sizes, int n_in,
                              void* d_out, int out_size, void* d_ws, size_t ws_size,
                              hipStream_t stream) {
    const float* vecs      = (const float*)d_in[0];
    const float* c_sum     = (const float*)d_in[1];
    const float* c_count   = (const float*)d_in[2];
    const float* loss_mask = (const float*)d_in[3];
    (void)in_sizes; (void)n_in; (void)out_size; (void)ws_size;

    char* ws = (char*)d_ws;
    float*          c        = (float*)(ws + WS_C_OFF);
    float*          c2       = (float*)(ws + WS_C2_OFF);
    unsigned short* cbh      = (unsigned short*)(ws + WS_CBH_OFF);
    unsigned short* cbl      = (unsigned short*)(ws + WS_CBL_OFF);
    float*          partials = (float*)(ws + WS_PART_OFF);

    float* out = (float*)d_out;
    float* out_vh      = out;                                   // B*H*L*DK
    float* out_z       = out + (size_t)Bc * Hc * Lc * DKc;      // B*H*L
    float* out_lcommit = out_z + (size_t)Bc * Hc * Lc;          // 1
    float* out_lcode   = out_lcommit + 1;                       // 1
    float* out_err     = out_lcode + 1;                         // B*H*L

    prep_kernel<<<(Hc * Sc * 64) / 256, 256, 0, stream>>>(c_sum, c_count, c, c2, cbh, cbl);

    vq_mfma_kernel<<<2048, 256, 0, stream>>>(vecs, c, c2, cbh, cbl, loss_mask,
                                             out_vh, out_z, out_err, partials);

    finalize_kernel<<<1, 256, 0, stream>>>(partials, NPART, out_lcommit, out_lcode);
}